// Round 1
// baseline (222.216 us; speedup 1.0000x reference)
//
#include <hip/hip_runtime.h>
#include <hip/hip_bf16.h>
#include <stdint.h>

#define IN_F   4096
#define OUT_F  768
#define OUTB   (OUT_F * 8)       // 6144
#define BATCH  1024
#define BK     64
#define NIT    (IN_F / BK)       // 64
#define NBLK_N (OUT_F / 64)      // 12
#define NBLK_M (BATCH / 64)      // 16
#define NBLK   (NBLK_N * NBLK_M) // 192

// ws layout (bytes):
//   0        : wp      ushort[IN_F*OUT_F]  packed [(k/8)][n][k%8]  (6.29 MB)
//   6291456  : labf    ushort[BATCH*IN_F]  bf16 latent row-major   (8.39 MB)
//   14680064 : regpart float[1536]
//   14686208 : ctrl    {float sqsum; uint ticket}   (zeroed by k_weights)
#define WS_LABF  6291456
#define WS_REGP  14680064
#define WS_CTRL  14686208

typedef short short8  __attribute__((ext_vector_type(8)));
typedef float f32x4   __attribute__((ext_vector_type(4)));
typedef unsigned int u32;

__device__ __forceinline__ ushort f2bf(float f) {
    uint32_t u = __builtin_bit_cast(uint32_t, f);
    u += 0x7FFFu + ((u >> 16) & 1u);
    return (ushort)(u >> 16);
}

__device__ __forceinline__ float waveReduceSum(float v) {
    #pragma unroll
    for (int off = 32; off > 0; off >>= 1) v += __shfl_down(v, off, 64);
    return v;
}

__device__ __forceinline__ void glds16(const void* g, void* l) {
    __builtin_amdgcn_global_load_lds(
        (const __attribute__((address_space(1))) u32*)g,
        (__attribute__((address_space(3))) u32*)l, 16, 0, 0);
}

// k_weights: blocks [0,1536): int_weights (bf16 packed [(k/8)][n][k%8]) + reg
// partials. blocks [1536,2048): latent fp32->bf16 conversion. Block 0 also
// zero-inits the ctrl words (workspace is poisoned between iterations).
__global__ __launch_bounds__(256) void k_weights(const float* __restrict__ w,
                                                 const float* __restrict__ latent,
                                                 ushort* __restrict__ wp,
                                                 ushort* __restrict__ labf,
                                                 float* __restrict__ regpart,
                                                 float* __restrict__ ctrl) {
    if (blockIdx.x == 0 && threadIdx.x == 0) {
        ctrl[0] = 0.f;                 // sqsum
        ((u32*)ctrl)[1] = 0u;          // ticket
    }
    if (blockIdx.x >= 1536) {
        int t = (blockIdx.x - 1536) * 256 + threadIdx.x;
        const float4* src = (const float4*)latent;
        uint4* dst = (uint4*)labf;
        #pragma unroll
        for (int j = 0; j < 4; j++) {
            int o = j * 131072 + t;
            float4 a0 = src[2 * o];
            float4 a1 = src[2 * o + 1];
            union { ushort u[8]; uint4 v; } pk;
            pk.u[0] = f2bf(a0.x); pk.u[1] = f2bf(a0.y); pk.u[2] = f2bf(a0.z); pk.u[3] = f2bf(a0.w);
            pk.u[4] = f2bf(a1.x); pk.u[5] = f2bf(a1.y); pk.u[6] = f2bf(a1.z); pk.u[7] = f2bf(a1.w);
            dst[o] = pk.v;
        }
        return;
    }

    int t  = blockIdx.x * 256 + threadIdx.x;
    int o  = t % OUT_F;
    int i8 = t / OUT_F;
    const float* src = w + (size_t)(i8 * 8) * OUTB + (size_t)o * 8;

    const float P[8] = {1.f, 2.f, 4.f, 8.f, 16.f, 32.f, 64.f, -128.f};
    float regsum = 0.f;
    union { ushort u[8]; uint4 v; } pk;

    #pragma unroll
    for (int r = 0; r < 8; r++) {
        float4 a = *(const float4*)(src + (size_t)r * OUTB);
        float4 b = *(const float4*)(src + (size_t)r * OUTB + 4);
        float x[8] = {a.x, a.y, a.z, a.w, b.x, b.y, b.z, b.w};
        float iw = 0.f;
        #pragma unroll
        for (int j = 0; j < 8; j++) {
            float p = __builtin_amdgcn_rcpf(1.f + __expf(-x[j]));
            iw += p * P[j];
            regsum += fminf(p, 1.f - p);
        }
        pk.u[r] = f2bf(iw);
    }
    *(uint4*)(wp + ((size_t)i8 * OUT_F + o) * 8) = pk.v;

    float ws = waveReduceSum(regsum);
    __shared__ float red[4];
    int lane = threadIdx.x & 63, wv = threadIdx.x >> 6;
    if (lane == 0) red[wv] = ws;
    __syncthreads();
    if (threadIdx.x == 0) regpart[blockIdx.x] = red[0] + red[1] + red[2] + red[3];
}

// k_gemm_epi: fused full-K bf16 MFMA GEMM (64x64 tile, BK=64, double-buffered,
// B staged via global_load_lds) + squared-error epilogue vs tsum + global
// atomic reduction; ticket-elected last block folds regpart and writes out.
// Grid = 192 blocks, XCD-chunked so same-A-panel blocks share an XCD L2.
__global__ __launch_bounds__(256) void k_gemm_epi(const ushort* __restrict__ labf,
                                                  const ushort* __restrict__ wp,
                                                  const float* __restrict__ tsum,
                                                  const float* __restrict__ regpart,
                                                  float* __restrict__ ctrl,
                                                  float* __restrict__ out) {
    __shared__ __align__(16) ushort lA[2][64 * 72];   // row stride 72
    __shared__ __align__(16) ushort lB[2][8 * 1032];  // plane stride 1032
    __shared__ float red[4];
    __shared__ int lastf;

    const int tid = threadIdx.x;
    // XCD-chunked swizzle: d%8 = XCD; each XCD owns 2 m-tiles x 12 n-tiles,
    // so all 12 blocks sharing an A panel sit on one XCD's L2.
    const int d  = blockIdx.x;
    const int xc = d & 7, s = d >> 3;            // s in [0,24)
    const int gm = xc + 8 * (s / NBLK_N);        // m-tile 0..15
    const int gn = s % NBLK_N;                   // n-tile 0..11
    const int n0 = gn * 64;
    const int m0 = gm * 64;
    const int lane = tid & 63, w = tid >> 6;
    const int wm = w >> 1, wn = w & 1;
    const int quad = lane >> 4, l16 = lane & 15;

    f32x4 acc[2][2] = {{{0.f,0.f,0.f,0.f},{0.f,0.f,0.f,0.f}},
                       {{0.f,0.f,0.f,0.f},{0.f,0.f,0.f,0.f}}};

    const int ar = tid >> 2, ac = tid & 3;            // A: row, 16-elem k-chunk
    const ushort* aptr = labf + (size_t)(m0 + ar) * IN_F + ac * 16;
    const ushort* bbase = wp + (size_t)(n0 + lane) * 8;

    int buf = 0;
    glds16(bbase + (size_t)(2 * w) * OUT_F * 8,     &lB[0][(2 * w) * 1032]);
    glds16(bbase + (size_t)(2 * w + 1) * OUT_F * 8, &lB[0][(2 * w + 1) * 1032]);
    {
        uint4 a0 = *(const uint4*)aptr;
        uint4 a1 = *(const uint4*)(aptr + 8);
        *(uint4*)&lA[0][ar * 72 + ac * 16]     = a0;
        *(uint4*)&lA[0][ar * 72 + ac * 16 + 8] = a1;
    }
    __syncthreads();

    #define MFMA_STEP(B)                                                                  \
        _Pragma("unroll")                                                                 \
        for (int ss = 0; ss < 2; ++ss) {                                                  \
            short8 af0 = *(short8*)&lA[B][(wm * 32 + l16) * 72 + ss * 32 + quad * 8];     \
            short8 af1 = *(short8*)&lA[B][(wm * 32 + 16 + l16) * 72 + ss * 32 + quad * 8];\
            short8 bf0 = *(short8*)&lB[B][(ss * 4 + quad) * 1032 + (wn * 32 + l16) * 8];  \
            short8 bf1 = *(short8*)&lB[B][(ss * 4 + quad) * 1032 + (wn * 32 + 16 + l16) * 8];\
            acc[0][0] = __builtin_amdgcn_mfma_f32_16x16x32_bf16(af0, bf0, acc[0][0], 0, 0, 0);\
            acc[0][1] = __builtin_amdgcn_mfma_f32_16x16x32_bf16(af0, bf1, acc[0][1], 0, 0, 0);\
            acc[1][0] = __builtin_amdgcn_mfma_f32_16x16x32_bf16(af1, bf0, acc[1][0], 0, 0, 0);\
            acc[1][1] = __builtin_amdgcn_mfma_f32_16x16x32_bf16(af1, bf1, acc[1][1], 0, 0, 0);\
        }

    #pragma unroll 2
    for (int it = 0; it < NIT - 1; ++it) {
        const int nxt = buf ^ 1;
        const ushort* bp = bbase + (size_t)(it + 1) * (8 * OUT_F * 8);
        glds16(bp + (size_t)(2 * w) * OUT_F * 8,     &lB[nxt][(2 * w) * 1032]);
        glds16(bp + (size_t)(2 * w + 1) * OUT_F * 8, &lB[nxt][(2 * w + 1) * 1032]);
        uint4 a0 = *(const uint4*)(aptr + (it + 1) * BK);
        uint4 a1 = *(const uint4*)(aptr + (it + 1) * BK + 8);
        MFMA_STEP(buf);
        *(uint4*)&lA[nxt][ar * 72 + ac * 16]     = a0;
        *(uint4*)&lA[nxt][ar * 72 + ac * 16 + 8] = a1;
        __syncthreads();
        buf = nxt;
    }
    MFMA_STEP(buf);
    #undef MFMA_STEP

    // ---- fused epilogue: sum (pred - isum)^2 over this tile ----
    float lsum = 0.f;
    #pragma unroll
    for (int fm = 0; fm < 2; fm++)
    #pragma unroll
    for (int fn = 0; fn < 2; fn++)
    #pragma unroll
    for (int r = 0; r < 4; r++) {
        int m = m0 + wm * 32 + fm * 16 + quad * 4 + r;
        int n = n0 + wn * 32 + fn * 16 + l16;
        const float* ts = tsum + (size_t)m * OUTB + (size_t)n * 8;
        float4 t0 = *(const float4*)ts;
        float4 t1 = *(const float4*)(ts + 4);
        float isum = t0.x + 2.f * t0.y + 4.f * t0.z + 8.f * t0.w
                   + 16.f * t1.x + 32.f * t1.y + 64.f * t1.z - 128.f * t1.w;
        float dv = acc[fm][fn][r] - isum;
        lsum += dv * dv;
    }
    float wsum = waveReduceSum(lsum);
    const int lane63 = tid & 63, wv = tid >> 6;
    if (lane63 == 0) red[wv] = wsum;
    __syncthreads();
    if (tid == 0) {
        float bsum = red[0] + red[1] + red[2] + red[3];
        atomicAdd(&ctrl[0], bsum);
        __threadfence();
        u32 old = atomicAdd(&((u32*)ctrl)[1], 1u);
        lastf = (old == (u32)(NBLK - 1));
    }
    __syncthreads();

    if (lastf) {   // last block: fold regpart + finalize outputs
        float r = 0.f;
        #pragma unroll
        for (int j = 0; j < 6; j++) r += regpart[tid + j * 256];
        r = waveReduceSum(r);
        __syncthreads();            // red[] reuse
        if (lane63 == 0) red[wv] = r;
        __syncthreads();
        if (tid == 0) {
            float S = atomicAdd(&ctrl[0], 0.0f);   // coherent read of final sum
            float R = red[0] + red[1] + red[2] + red[3];
            float recon = S / ((float)(BATCH * OUT_F) * 255.f * 255.f);
            float reg   = 0.001f * R / (float)((size_t)IN_F * OUTB);
            out[0] = recon + reg;
            out[1] = recon;
            out[2] = reg;
        }
    }
}

extern "C" void kernel_launch(void* const* d_in, const int* in_sizes, int n_in,
                              void* d_out, int out_size, void* d_ws, size_t ws_size,
                              hipStream_t stream) {
    const float* latent = (const float*)d_in[0];   // [1024, 4096]
    const float* tsum   = (const float*)d_in[1];   // [1024, 6144]
    const float* weight = (const float*)d_in[2];   // [4096, 6144]
    float* out      = (float*)d_out;
    ushort* wp      = (ushort*)d_ws;
    ushort* labf    = (ushort*)((char*)d_ws + WS_LABF);
    float* regpart  = (float*)((char*)d_ws + WS_REGP);
    float* ctrl     = (float*)((char*)d_ws + WS_CTRL);

    k_weights<<<2048, 256, 0, stream>>>(weight, latent, wp, labf, regpart, ctrl);
    k_gemm_epi<<<NBLK, 256, 0, stream>>>(labf, wp, tsum, regpart, ctrl, out);
}